// Round 1
// 678.957 us; speedup vs baseline: 1.2124x; 1.2124x over previous
//
#include <hip/hip_runtime.h>
#include <hip/hip_bf16.h>

typedef __hip_bfloat16 bf16;
typedef __attribute__((ext_vector_type(8))) short short8;
typedef __attribute__((ext_vector_type(4))) float f32x4;

__device__ __forceinline__ float bfu(unsigned short b) {
    unsigned u = ((unsigned)b) << 16;
    float f;
    __builtin_memcpy(&f, &u, 4);
    return f;
}
__device__ __forceinline__ unsigned short f2b(float f) {
    return (unsigned short)(__hip_bfloat16_raw(__float2bfloat16(f)).x);
}

// async global->LDS, 16B per lane; lds dest must be wave-uniform base.
__device__ __forceinline__ void gl_lds16(const void* g, void* l) {
    __builtin_amdgcn_global_load_lds(
        (const __attribute__((address_space(1))) void*)g,
        (__attribute__((address_space(3))) void*)l, 16, 0, 0);
}

// ---------------------------------------------------------------------------
// Threefry-2x32 (20 rounds), JAX partitionable: keep = top bit of (x0^x1)==0
// ---------------------------------------------------------------------------
__device__ __forceinline__ bool keep_elem(unsigned idx) {
    const unsigned k0 = 0u, k1 = 42u;
    const unsigned k2 = k0 ^ k1 ^ 0x1BD11BDAu;
    unsigned x0 = k0;
    unsigned x1 = idx + k1;
#define TF_QR(R) { x0 += x1; x1 = (x1 << R) | (x1 >> (32 - R)); x1 ^= x0; }
    TF_QR(13) TF_QR(15) TF_QR(26) TF_QR(6)
    x0 += k1; x1 += k2 + 1u;
    TF_QR(17) TF_QR(29) TF_QR(16) TF_QR(24)
    x0 += k2; x1 += k0 + 2u;
    TF_QR(13) TF_QR(15) TF_QR(26) TF_QR(6)
    x0 += k0; x1 += k1 + 3u;
    TF_QR(17) TF_QR(29) TF_QR(16) TF_QR(24)
    x0 += k1; x1 += k2 + 4u;
    TF_QR(13) TF_QR(15) TF_QR(26) TF_QR(6)
    x0 += k2; x1 += k0 + 5u;
#undef TF_QR
    return (((x0 ^ x1) >> 31) & 1u) == 0u;
}

// ---------------------------------------------------------------------------
// Dtype detection: flag[0] edges int64?, flag[1] x f32?, flag[2] weights f32?
// ---------------------------------------------------------------------------
__global__ void detect_edges_k(const unsigned* __restrict__ w, int* __restrict__ flag) {
    __shared__ unsigned red[256];
    unsigned v = 0;
    for (int i = threadIdx.x; i < 2048; i += 256) v |= w[2 * i + 1];
    red[threadIdx.x] = v;
    __syncthreads();
    for (int s = 128; s > 0; s >>= 1) {
        if (threadIdx.x < s) red[threadIdx.x] |= red[threadIdx.x + s];
        __syncthreads();
    }
    if (threadIdx.x == 0) flag[0] = (red[0] == 0u) ? 1 : 0;
}

__global__ void detect_f32_k(const unsigned short* __restrict__ w,
                             int* __restrict__ flag, int fidx) {
    __shared__ int red[256];
    int cnt = 0;
    for (int i = threadIdx.x; i < 1024; i += 256) {
        unsigned short b = w[2 * i];
        int e = (b >> 7) & 0xFF;
        if ((b & 0x7FFF) == 0 || (e >= 100 && e < 140)) cnt++;
    }
    red[threadIdx.x] = cnt;
    __syncthreads();
    for (int s = 128; s > 0; s >>= 1) {
        if (threadIdx.x < s) red[threadIdx.x] += red[threadIdx.x + s];
        __syncthreads();
    }
    if (threadIdx.x == 0) flag[fidx] = (red[0] < 614) ? 1 : 0;
}

__global__ void convert_edges_k(const void* __restrict__ src, int* __restrict__ out,
                                int twoE, const int* __restrict__ flag) {
    int i = blockIdx.x * 256 + threadIdx.x;
    if (i >= twoE) return;
    if (flag[0]) out[i] = (int)((const unsigned long long*)src)[i];
    else         out[i] = ((const int*)src)[i];
}

// canonicalize x to bf16 AND apply dropout mask (x2 is exact in bf16).
// Vectorized: 8 elements per thread (32B f32 read or 16B bf16 read; 16B write).
__global__ void canon_x_drop_k(const void* __restrict__ src, bf16* __restrict__ dst,
                               int n8, const int* __restrict__ flag) {
    int i = blockIdx.x * 256 + threadIdx.x;
    if (i >= n8) return;
    float v[8];
    if (flag[1]) {
        const f32x4* p = (const f32x4*)src;
        f32x4 a = p[2 * i], b = p[2 * i + 1];
#pragma unroll
        for (int k = 0; k < 4; ++k) { v[k] = a[k]; v[4 + k] = b[k]; }
    } else {
        short8 u = ((const short8*)src)[i];
#pragma unroll
        for (int k = 0; k < 8; ++k) v[k] = bfu((unsigned short)u[k]);
    }
    unsigned base = (unsigned)i * 8u;
    short8 o;
#pragma unroll
    for (int k = 0; k < 8; ++k) {
        float f = keep_elem(base + k) ? v[k] * 2.0f : 0.0f;
        o[k] = (short)f2b(f);
    }
    ((short8*)dst)[i] = o;
}

__global__ void canon_k(const void* __restrict__ src, bf16* __restrict__ dst,
                        int n, const int* __restrict__ flag, int fidx) {
    int i = blockIdx.x * 256 + threadIdx.x;
    if (i >= n) return;
    if (flag[fidx]) dst[i] = __float2bfloat16(((const float*)src)[i]);
    else            dst[i] = ((const bf16*)src)[i];
}

// canonicalize + transpose weight [K,Nn] -> [Nn,K] (both multiples of 16)
__global__ void canon_transpose_k(const void* __restrict__ src, unsigned short* __restrict__ dst,
                                  int K, int Nn, const int* __restrict__ flag, int fidx) {
    __shared__ unsigned short tile[16][17];
    int k0 = blockIdx.x * 16, n0 = blockIdx.y * 16;
    int k = k0 + threadIdx.y, n = n0 + threadIdx.x;
    unsigned short v;
    if (flag[fidx]) v = f2b(((const float*)src)[(size_t)k * Nn + n]);
    else            v = ((const unsigned short*)src)[(size_t)k * Nn + n];
    tile[threadIdx.y][threadIdx.x] = v;
    __syncthreads();
    int nn = n0 + threadIdx.y, kk = k0 + threadIdx.x;
    dst[(size_t)nn * K + kk] = tile[threadIdx.x][threadIdx.y];
}

// ---------------------------------------------------------------------------
// CSR build
// ---------------------------------------------------------------------------
__global__ void zero_int_k(int* __restrict__ p, int n) {
    int i = blockIdx.x * 256 + threadIdx.x;
    if (i < n) p[i] = 0;
}
__global__ void deg_count_k(const int* __restrict__ edges, int* __restrict__ degi,
                            int E, int n) {
    int e = blockIdx.x * 256 + threadIdx.x;
    if (e >= E) return;
    int d = edges[E + e];
    d = (d < 0) ? 0 : (d >= n ? n - 1 : d);
    atomicAdd(&degi[d], 1);
}
__global__ void dinv_k(const int* __restrict__ degi, float* __restrict__ dinv, int n) {
    int i = blockIdx.x * 256 + threadIdx.x;
    if (i < n) dinv[i] = rsqrtf(1.0f + (float)degi[i]);
}
__global__ void block_sums_k(const int* __restrict__ deg, int* __restrict__ partial, int n) {
    __shared__ int sh[256];
    int i = blockIdx.x * 256 + threadIdx.x;
    sh[threadIdx.x] = (i < n) ? deg[i] : 0;
    __syncthreads();
    for (int s = 128; s > 0; s >>= 1) {
        if (threadIdx.x < s) sh[threadIdx.x] += sh[threadIdx.x + s];
        __syncthreads();
    }
    if (threadIdx.x == 0) partial[blockIdx.x] = sh[0];
}
__global__ void scan_partials_k(int* __restrict__ partial, int G) {
    __shared__ int sh[256];
    int v = (threadIdx.x < G) ? partial[threadIdx.x] : 0;
    sh[threadIdx.x] = v;
    __syncthreads();
    for (int s = 1; s < 256; s <<= 1) {
        int t = 0;
        if (threadIdx.x >= s) t = sh[threadIdx.x - s];
        __syncthreads();
        sh[threadIdx.x] += t;
        __syncthreads();
    }
    if (threadIdx.x < G) partial[threadIdx.x] = sh[threadIdx.x] - v;
}
__global__ void scan_block_k(const int* __restrict__ deg, const int* __restrict__ partial,
                             int* __restrict__ row_ptr, int n) {
    __shared__ int sh[256];
    int i = blockIdx.x * 256 + threadIdx.x;
    int v = (i < n) ? deg[i] : 0;
    sh[threadIdx.x] = v;
    __syncthreads();
    for (int s = 1; s < 256; s <<= 1) {
        int t = 0;
        if (threadIdx.x >= s) t = sh[threadIdx.x - s];
        __syncthreads();
        sh[threadIdx.x] += t;
        __syncthreads();
    }
    int incl = sh[threadIdx.x];
    int base = partial[blockIdx.x];
    if (i < n) row_ptr[i] = base + incl - v;
    if (i == n - 1) row_ptr[n] = base + incl;
}
__global__ void fill_k(const int* __restrict__ edges, const int* __restrict__ row_ptr,
                       int* __restrict__ cnt, int* __restrict__ col, int E, int n) {
    int e = blockIdx.x * 256 + threadIdx.x;
    if (e >= E) return;
    int s = edges[e], d = edges[E + e];
    s = (s < 0) ? 0 : (s >= n ? n - 1 : s);
    d = (d < 0) ? 0 : (d >= n ? n - 1 : d);
    int pos = row_ptr[d] + atomicAdd(&cnt[d], 1);
    col[pos] = s;
}

// ---------------------------------------------------------------------------
// MFMA GEMM (m97 structure): C[M,Nn] = A[M,K] @ Bt[Nn,K]^T
// 128x128 tile, BK=32, 4 waves in 2x2, each wave 4x4 of 16x16x32 bf16 MFMA.
// Epilogue: Cf!=null -> f32 out + bf16 bias; else bf16 out.
// ---------------------------------------------------------------------------
__global__ __launch_bounds__(256) void gemm_mfma_k(
    const bf16* __restrict__ A, const bf16* __restrict__ Bt,
    bf16* __restrict__ Cb, float* __restrict__ Cf, const bf16* __restrict__ bias,
    int M, int Nn, int K) {
    __shared__ short sA[128 * 32];
    __shared__ short sB[128 * 32];
    const int tid = threadIdx.x;
    const int lane = tid & 63;
    const int w = tid >> 6;
    const int m0 = blockIdx.x * 128;
    const int n0 = blockIdx.y * 128;
    const int wm = (w >> 1) * 64;
    const int wn = (w & 1) * 64;

    f32x4 acc[4][4] = {};

    const int srow = lane >> 2;        // 0..15 within a 16-row group
    const int scol = (lane & 3) * 8;   // k offset 0/8/16/24

    for (int kk = 0; kk < K; kk += 32) {
#pragma unroll
        for (int q = 0; q < 2; ++q) {  // A tile: rows q*64 + w*16 + srow
            int r = q * 64 + w * 16 + srow;
            int grow = m0 + r; if (grow >= M) grow = M - 1;
            gl_lds16(A + (size_t)grow * K + kk + scol, &sA[q * 2048 + w * 512 + lane * 8]);
        }
#pragma unroll
        for (int q = 0; q < 2; ++q) {  // B tile (Nn multiple of 128, no clamp)
            int r = q * 64 + w * 16 + srow;
            gl_lds16(Bt + (size_t)(n0 + r) * K + kk + scol, &sB[q * 2048 + w * 512 + lane * 8]);
        }
        __syncthreads();

        const int fr = lane & 15;
        const int fk = (lane >> 4) * 8;
        short8 af[4], bfr[4];
#pragma unroll
        for (int i = 0; i < 4; ++i)
            af[i] = *(const short8*)&sA[(wm + i * 16 + fr) * 32 + fk];
#pragma unroll
        for (int j = 0; j < 4; ++j)
            bfr[j] = *(const short8*)&sB[(wn + j * 16 + fr) * 32 + fk];
#pragma unroll
        for (int i = 0; i < 4; ++i)
#pragma unroll
            for (int j = 0; j < 4; ++j)
                acc[i][j] = __builtin_amdgcn_mfma_f32_16x16x32_bf16(
                    af[i], bfr[j], acc[i][j], 0, 0, 0);
        __syncthreads();
    }

    const int crow = (lane >> 4) * 4;
    const int ccol = lane & 15;
#pragma unroll
    for (int i = 0; i < 4; ++i) {
#pragma unroll
        for (int r = 0; r < 4; ++r) {
            int row = m0 + wm + i * 16 + crow + r;
            if (row >= M) continue;
            if (Cf) {
                float* cp = Cf + (size_t)row * Nn + n0 + wn;
#pragma unroll
                for (int j = 0; j < 4; ++j) {
                    int c = j * 16 + ccol;
                    cp[c] = acc[i][j][r] + __bfloat162float(bias[n0 + wn + c]);
                }
            } else {
                bf16* cp = Cb + (size_t)row * Nn + n0 + wn;
#pragma unroll
                for (int j = 0; j < 4; ++j)
                    cp[j * 16 + ccol] = __float2bfloat16(acc[i][j][r]);
            }
        }
    }
}

// ---------------------------------------------------------------------------
// CSR gather: out[node] = sum_edges dinv[s]*dinv[node]*t[s] + dinv[node]^2*t[node]
// (+bias, relu if mode==1).
// One WAVE per node; each lane owns 8 consecutive bf16 feats (16B loads).
// Edge loop unrolled x4 so 4 x 1KB row reads stay in flight per wave
// (latency-bound fix: ~16x more bytes outstanding than the ushort2 version).
// ---------------------------------------------------------------------------
__global__ __launch_bounds__(256) void gather_k(
    const bf16* __restrict__ t, const int* __restrict__ row_ptr,
    const int* __restrict__ col, const float* __restrict__ dinv,
    const bf16* __restrict__ bias, bf16* __restrict__ outp, int mode, int N) {
    const int node = blockIdx.x * 4 + (threadIdx.x >> 6);
    if (node >= N) return;
    const int lane = threadIdx.x & 63;
    const short8* tp = (const short8*)t;
    const int beg = row_ptr[node];
    const int end = row_ptr[node + 1];
    const float dv = dinv[node];
    float acc[8] = {0.f, 0.f, 0.f, 0.f, 0.f, 0.f, 0.f, 0.f};

    int e = beg;
    for (; e + 4 <= end; e += 4) {
        int s0 = col[e + 0], s1 = col[e + 1], s2 = col[e + 2], s3 = col[e + 3];
        float w0 = dinv[s0] * dv, w1 = dinv[s1] * dv;
        float w2 = dinv[s2] * dv, w3 = dinv[s3] * dv;
        short8 u0 = tp[(size_t)s0 * 64 + lane];
        short8 u1 = tp[(size_t)s1 * 64 + lane];
        short8 u2 = tp[(size_t)s2 * 64 + lane];
        short8 u3 = tp[(size_t)s3 * 64 + lane];
#pragma unroll
        for (int k = 0; k < 8; ++k) {
            acc[k] += w0 * bfu((unsigned short)u0[k]);
            acc[k] += w1 * bfu((unsigned short)u1[k]);
            acc[k] += w2 * bfu((unsigned short)u2[k]);
            acc[k] += w3 * bfu((unsigned short)u3[k]);
        }
    }
    for (; e < end; ++e) {
        int s = col[e];
        float w = dinv[s] * dv;
        short8 u = tp[(size_t)s * 64 + lane];
#pragma unroll
        for (int k = 0; k < 8; ++k) acc[k] += w * bfu((unsigned short)u[k]);
    }
    {   // self loop
        short8 u = tp[(size_t)node * 64 + lane];
        float w = dv * dv;
#pragma unroll
        for (int k = 0; k < 8; ++k) acc[k] += w * bfu((unsigned short)u[k]);
    }
    if (mode == 1) {
        short8 bs = ((const short8*)bias)[lane];
#pragma unroll
        for (int k = 0; k < 8; ++k) {
            acc[k] += bfu((unsigned short)bs[k]);
            acc[k] = fmaxf(acc[k], 0.f);
        }
    }
    short8 o;
#pragma unroll
    for (int k = 0; k < 8; ++k) o[k] = (short)f2b(acc[k]);
    ((short8*)outp)[(size_t)node * 64 + lane] = o;
}

// ---------------------------------------------------------------------------
extern "C" void kernel_launch(void* const* d_in, const int* in_sizes, int n_in,
                              void* d_out, int out_size, void* d_ws, size_t ws_size,
                              hipStream_t stream) {
    const void* xin   = d_in[0];
    const void* ei    = d_in[1];
    const void* W1in  = d_in[2];
    const void* b1in  = d_in[3];
    const void* Wmuin = d_in[4];
    const void* bmuin = d_in[5];
    const void* Wlsin = d_in[6];
    const void* blsin = d_in[7];
    float* out = (float*)d_out;

    const int H    = in_sizes[3];        // 512
    const int DOUT = in_sizes[5];        // 256
    const int DIN  = in_sizes[2] / H;    // 512
    const int N    = in_sizes[0] / DIN;  // 50000
    const int E    = in_sizes[1] / 2;    // 800000
    const int G    = (N + 255) / 256;

    char* ws = (char*)d_ws;
    size_t off = 0;
    auto alloc = [&](size_t bytes) {
        void* p = ws + off;
        off = (off + bytes + 255) & ~(size_t)255;
        return p;
    };
    int*   flag    = (int*)alloc(256);
    int*   edges   = (int*)alloc((size_t)2 * E * 4);
    int*   degi    = (int*)alloc((size_t)N * 4);
    int*   row_ptr = (int*)alloc((size_t)(N + 1) * 4);
    int*   cnt     = (int*)alloc((size_t)N * 4);
    int*   partial = (int*)alloc((size_t)G * 4);
    int*   col     = (int*)alloc((size_t)E * 4);
    float* dinv    = (float*)alloc((size_t)N * 4);
    bf16*  t1      = (bf16*)alloc((size_t)N * H * 2);
    bf16*  g1      = (bf16*)alloc((size_t)N * H * 2);
    bf16*  xdrop   = (bf16*)alloc((size_t)N * DIN * 2);  // reused as h1
    bf16*  W1t     = (bf16*)alloc((size_t)DIN * H * 2);  // [H, DIN]
    bf16*  Wmut    = (bf16*)alloc((size_t)H * DOUT * 2); // [DOUT, H]
    bf16*  Wlst    = (bf16*)alloc((size_t)H * DOUT * 2);
    bf16*  b1c     = (bf16*)alloc((size_t)H * 2);
    bf16*  bmuc    = (bf16*)alloc((size_t)DOUT * 2);
    bf16*  blsc    = (bf16*)alloc((size_t)DOUT * 2);
    if (off > ws_size) return;

    const int twoE = 2 * E;
    hipLaunchKernelGGL(detect_edges_k, dim3(1), dim3(256), 0, stream, (const unsigned*)ei, flag);
    hipLaunchKernelGGL(detect_f32_k, dim3(1), dim3(256), 0, stream, (const unsigned short*)xin, flag, 1);
    hipLaunchKernelGGL(detect_f32_k, dim3(1), dim3(256), 0, stream, (const unsigned short*)W1in, flag, 2);

    hipLaunchKernelGGL(convert_edges_k, dim3((twoE + 255) / 256), dim3(256), 0, stream,
                       ei, edges, twoE, flag);
    int n8 = (N * DIN) / 8;
    hipLaunchKernelGGL(canon_x_drop_k, dim3((n8 + 255) / 256), dim3(256), 0, stream,
                       xin, xdrop, n8, flag);
    hipLaunchKernelGGL(canon_transpose_k, dim3(DIN / 16, H / 16), dim3(16, 16), 0, stream,
                       W1in, (unsigned short*)W1t, DIN, H, flag, 2);
    hipLaunchKernelGGL(canon_transpose_k, dim3(H / 16, DOUT / 16), dim3(16, 16), 0, stream,
                       Wmuin, (unsigned short*)Wmut, H, DOUT, flag, 2);
    hipLaunchKernelGGL(canon_transpose_k, dim3(H / 16, DOUT / 16), dim3(16, 16), 0, stream,
                       Wlsin, (unsigned short*)Wlst, H, DOUT, flag, 2);
    hipLaunchKernelGGL(canon_k, dim3(2), dim3(256), 0, stream, b1in, b1c, H, flag, 2);
    hipLaunchKernelGGL(canon_k, dim3(1), dim3(256), 0, stream, bmuin, bmuc, DOUT, flag, 2);
    hipLaunchKernelGGL(canon_k, dim3(1), dim3(256), 0, stream, blsin, blsc, DOUT, flag, 2);

    // CSR build
    hipLaunchKernelGGL(zero_int_k, dim3(G), dim3(256), 0, stream, degi, N);
    hipLaunchKernelGGL(zero_int_k, dim3(G), dim3(256), 0, stream, cnt, N);
    hipLaunchKernelGGL(deg_count_k, dim3((E + 255) / 256), dim3(256), 0, stream, edges, degi, E, N);
    hipLaunchKernelGGL(dinv_k, dim3(G), dim3(256), 0, stream, degi, dinv, N);
    hipLaunchKernelGGL(block_sums_k, dim3(G), dim3(256), 0, stream, degi, partial, N);
    hipLaunchKernelGGL(scan_partials_k, dim3(1), dim3(256), 0, stream, partial, G);
    hipLaunchKernelGGL(scan_block_k, dim3(G), dim3(256), 0, stream, degi, partial, row_ptr, N);
    hipLaunchKernelGGL(fill_k, dim3((E + 255) / 256), dim3(256), 0, stream, edges, row_ptr, cnt, col, E, N);

    // layer 1: t1 = xdrop @ W1 ; h1 = relu(gather(t1) + b1)
    hipLaunchKernelGGL(gemm_mfma_k, dim3((N + 127) / 128, H / 128), dim3(256), 0, stream,
                       xdrop, W1t, t1, (float*)nullptr, (const bf16*)nullptr, N, H, DIN);
    bf16* h1 = xdrop;
    hipLaunchKernelGGL(gather_k, dim3((N + 3) / 4), dim3(256), 0, stream,
                       t1, row_ptr, col, dinv, b1c, h1, 1, N);

    // layer 2: g1 = gather(h1); mu = g1@Wmu + bmu ; logstd = g1@Wls + bls
    hipLaunchKernelGGL(gather_k, dim3((N + 3) / 4), dim3(256), 0, stream,
                       h1, row_ptr, col, dinv, (const bf16*)nullptr, g1, 0, N);
    hipLaunchKernelGGL(gemm_mfma_k, dim3((N + 127) / 128, DOUT / 128), dim3(256), 0, stream,
                       g1, Wmut, (bf16*)nullptr, out, bmuc, N, DOUT, H);
    hipLaunchKernelGGL(gemm_mfma_k, dim3((N + 127) / 128, DOUT / 128), dim3(256), 0, stream,
                       g1, Wlst, (bf16*)nullptr, out + (size_t)N * DOUT, blsc, N, DOUT, H);
}

// Round 2
// 659.059 us; speedup vs baseline: 1.2490x; 1.0302x over previous
//
#include <hip/hip_runtime.h>
#include <hip/hip_bf16.h>

typedef __hip_bfloat16 bf16;
typedef __attribute__((ext_vector_type(8))) short short8;
typedef __attribute__((ext_vector_type(4))) float f32x4;

__device__ __forceinline__ float bfu(unsigned short b) {
    unsigned u = ((unsigned)b) << 16;
    float f;
    __builtin_memcpy(&f, &u, 4);
    return f;
}
__device__ __forceinline__ unsigned short f2b(float f) {
    return (unsigned short)(__hip_bfloat16_raw(__float2bfloat16(f)).x);
}

// async global->LDS, 16B per lane; lds dest must be wave-uniform base.
__device__ __forceinline__ void gl_lds16(const void* g, void* l) {
    __builtin_amdgcn_global_load_lds(
        (const __attribute__((address_space(1))) void*)g,
        (__attribute__((address_space(3))) void*)l, 16, 0, 0);
}

// ---------------------------------------------------------------------------
// Threefry-2x32 (20 rounds), JAX partitionable: keep = top bit of (x0^x1)==0
// ---------------------------------------------------------------------------
__device__ __forceinline__ bool keep_elem(unsigned idx) {
    const unsigned k0 = 0u, k1 = 42u;
    const unsigned k2 = k0 ^ k1 ^ 0x1BD11BDAu;
    unsigned x0 = k0;
    unsigned x1 = idx + k1;
#define TF_QR(R) { x0 += x1; x1 = (x1 << R) | (x1 >> (32 - R)); x1 ^= x0; }
    TF_QR(13) TF_QR(15) TF_QR(26) TF_QR(6)
    x0 += k1; x1 += k2 + 1u;
    TF_QR(17) TF_QR(29) TF_QR(16) TF_QR(24)
    x0 += k2; x1 += k0 + 2u;
    TF_QR(13) TF_QR(15) TF_QR(26) TF_QR(6)
    x0 += k0; x1 += k1 + 3u;
    TF_QR(17) TF_QR(29) TF_QR(16) TF_QR(24)
    x0 += k1; x1 += k2 + 4u;
    TF_QR(13) TF_QR(15) TF_QR(26) TF_QR(6)
    x0 += k2; x1 += k0 + 5u;
#undef TF_QR
    return (((x0 ^ x1) >> 31) & 1u) == 0u;
}

// ---------------------------------------------------------------------------
// Dtype detection: flag[0] edges int64?, flag[1] x f32?, flag[2] weights f32?
// ---------------------------------------------------------------------------
__global__ void detect_edges_k(const unsigned* __restrict__ w, int* __restrict__ flag) {
    __shared__ unsigned red[256];
    unsigned v = 0;
    for (int i = threadIdx.x; i < 2048; i += 256) v |= w[2 * i + 1];
    red[threadIdx.x] = v;
    __syncthreads();
    for (int s = 128; s > 0; s >>= 1) {
        if (threadIdx.x < s) red[threadIdx.x] |= red[threadIdx.x + s];
        __syncthreads();
    }
    if (threadIdx.x == 0) flag[0] = (red[0] == 0u) ? 1 : 0;
}

__global__ void detect_f32_k(const unsigned short* __restrict__ w,
                             int* __restrict__ flag, int fidx) {
    __shared__ int red[256];
    int cnt = 0;
    for (int i = threadIdx.x; i < 1024; i += 256) {
        unsigned short b = w[2 * i];
        int e = (b >> 7) & 0xFF;
        if ((b & 0x7FFF) == 0 || (e >= 100 && e < 140)) cnt++;
    }
    red[threadIdx.x] = cnt;
    __syncthreads();
    for (int s = 128; s > 0; s >>= 1) {
        if (threadIdx.x < s) red[threadIdx.x] += red[threadIdx.x + s];
        __syncthreads();
    }
    if (threadIdx.x == 0) flag[fidx] = (red[0] < 614) ? 1 : 0;
}

__global__ void convert_edges_k(const void* __restrict__ src, int* __restrict__ out,
                                int twoE, const int* __restrict__ flag) {
    int i = blockIdx.x * 256 + threadIdx.x;
    if (i >= twoE) return;
    if (flag[0]) out[i] = (int)((const unsigned long long*)src)[i];
    else         out[i] = ((const int*)src)[i];
}

// canonicalize x to bf16 AND apply dropout mask (x2 is exact in bf16).
// Vectorized: 8 elements per thread (32B f32 read or 16B bf16 read; 16B write).
__global__ void canon_x_drop_k(const void* __restrict__ src, bf16* __restrict__ dst,
                               int n8, const int* __restrict__ flag) {
    int i = blockIdx.x * 256 + threadIdx.x;
    if (i >= n8) return;
    float v[8];
    if (flag[1]) {
        const f32x4* p = (const f32x4*)src;
        f32x4 a = p[2 * i], b = p[2 * i + 1];
#pragma unroll
        for (int k = 0; k < 4; ++k) { v[k] = a[k]; v[4 + k] = b[k]; }
    } else {
        short8 u = ((const short8*)src)[i];
#pragma unroll
        for (int k = 0; k < 8; ++k) v[k] = bfu((unsigned short)u[k]);
    }
    unsigned base = (unsigned)i * 8u;
    short8 o;
#pragma unroll
    for (int k = 0; k < 8; ++k) {
        float f = keep_elem(base + k) ? v[k] * 2.0f : 0.0f;
        o[k] = (short)f2b(f);
    }
    ((short8*)dst)[i] = o;
}

__global__ void canon_k(const void* __restrict__ src, bf16* __restrict__ dst,
                        int n, const int* __restrict__ flag, int fidx) {
    int i = blockIdx.x * 256 + threadIdx.x;
    if (i >= n) return;
    if (flag[fidx]) dst[i] = __float2bfloat16(((const float*)src)[i]);
    else            dst[i] = ((const bf16*)src)[i];
}

// canonicalize + transpose weight [K,Nn] -> [Nn,K] (both multiples of 16)
__global__ void canon_transpose_k(const void* __restrict__ src, unsigned short* __restrict__ dst,
                                  int K, int Nn, const int* __restrict__ flag, int fidx) {
    __shared__ unsigned short tile[16][17];
    int k0 = blockIdx.x * 16, n0 = blockIdx.y * 16;
    int k = k0 + threadIdx.y, n = n0 + threadIdx.x;
    unsigned short v;
    if (flag[fidx]) v = f2b(((const float*)src)[(size_t)k * Nn + n]);
    else            v = ((const unsigned short*)src)[(size_t)k * Nn + n];
    tile[threadIdx.y][threadIdx.x] = v;
    __syncthreads();
    int nn = n0 + threadIdx.y, kk = k0 + threadIdx.x;
    dst[(size_t)nn * K + kk] = tile[threadIdx.x][threadIdx.y];
}

// ---------------------------------------------------------------------------
// CSR build
// ---------------------------------------------------------------------------
__global__ void zero_int_k(int* __restrict__ p, int n) {
    int i = blockIdx.x * 256 + threadIdx.x;
    if (i < n) p[i] = 0;
}
__global__ void deg_count_k(const int* __restrict__ edges, int* __restrict__ degi,
                            int E, int n) {
    int e = blockIdx.x * 256 + threadIdx.x;
    if (e >= E) return;
    int d = edges[E + e];
    d = (d < 0) ? 0 : (d >= n ? n - 1 : d);
    atomicAdd(&degi[d], 1);
}
__global__ void dinv_k(const int* __restrict__ degi, float* __restrict__ dinv, int n) {
    int i = blockIdx.x * 256 + threadIdx.x;
    if (i < n) dinv[i] = rsqrtf(1.0f + (float)degi[i]);
}
__global__ void block_sums_k(const int* __restrict__ deg, int* __restrict__ partial, int n) {
    __shared__ int sh[256];
    int i = blockIdx.x * 256 + threadIdx.x;
    sh[threadIdx.x] = (i < n) ? deg[i] : 0;
    __syncthreads();
    for (int s = 128; s > 0; s >>= 1) {
        if (threadIdx.x < s) sh[threadIdx.x] += sh[threadIdx.x + s];
        __syncthreads();
    }
    if (threadIdx.x == 0) partial[blockIdx.x] = sh[0];
}
__global__ void scan_partials_k(int* __restrict__ partial, int G) {
    __shared__ int sh[256];
    int v = (threadIdx.x < G) ? partial[threadIdx.x] : 0;
    sh[threadIdx.x] = v;
    __syncthreads();
    for (int s = 1; s < 256; s <<= 1) {
        int t = 0;
        if (threadIdx.x >= s) t = sh[threadIdx.x - s];
        __syncthreads();
        sh[threadIdx.x] += t;
        __syncthreads();
    }
    if (threadIdx.x < G) partial[threadIdx.x] = sh[threadIdx.x] - v;
}
__global__ void scan_block_k(const int* __restrict__ deg, const int* __restrict__ partial,
                             int* __restrict__ row_ptr, int n) {
    __shared__ int sh[256];
    int i = blockIdx.x * 256 + threadIdx.x;
    int v = (i < n) ? deg[i] : 0;
    sh[threadIdx.x] = v;
    __syncthreads();
    for (int s = 1; s < 256; s <<= 1) {
        int t = 0;
        if (threadIdx.x >= s) t = sh[threadIdx.x - s];
        __syncthreads();
        sh[threadIdx.x] += t;
        __syncthreads();
    }
    int incl = sh[threadIdx.x];
    int base = partial[blockIdx.x];
    if (i < n) row_ptr[i] = base + incl - v;
    if (i == n - 1) row_ptr[n] = base + incl;
}
__global__ void fill_k(const int* __restrict__ edges, const int* __restrict__ row_ptr,
                       int* __restrict__ cnt, int* __restrict__ col, int E, int n) {
    int e = blockIdx.x * 256 + threadIdx.x;
    if (e >= E) return;
    int s = edges[e], d = edges[E + e];
    s = (s < 0) ? 0 : (s >= n ? n - 1 : s);
    d = (d < 0) ? 0 : (d >= n ? n - 1 : d);
    int pos = row_ptr[d] + atomicAdd(&cnt[d], 1);
    col[pos] = s;
}

// ---------------------------------------------------------------------------
// MFMA GEMM (m97 structure): C[M,Nn] = A[M,K] @ Bt[Nn,K]^T
// 128x128 tile, BK=32, 4 waves in 2x2, each wave 4x4 of 16x16x32 bf16 MFMA.
// Epilogue: Cf!=null -> f32 out + bf16 bias; else bf16 out.
// If Cf2!=null: columns [0,split) -> Cf (row stride split), [split,Nn) -> Cf2.
// ---------------------------------------------------------------------------
__global__ __launch_bounds__(256) void gemm_mfma_k(
    const bf16* __restrict__ A, const bf16* __restrict__ Bt,
    bf16* __restrict__ Cb, float* __restrict__ Cf, float* __restrict__ Cf2,
    const bf16* __restrict__ bias, int M, int Nn, int K, int split) {
    __shared__ short sA[128 * 32];
    __shared__ short sB[128 * 32];
    const int tid = threadIdx.x;
    const int lane = tid & 63;
    const int w = tid >> 6;
    const int m0 = blockIdx.x * 128;
    const int n0 = blockIdx.y * 128;
    const int wm = (w >> 1) * 64;
    const int wn = (w & 1) * 64;

    f32x4 acc[4][4] = {};

    const int srow = lane >> 2;        // 0..15 within a 16-row group
    const int scol = (lane & 3) * 8;   // k offset 0/8/16/24

    for (int kk = 0; kk < K; kk += 32) {
#pragma unroll
        for (int q = 0; q < 2; ++q) {  // A tile: rows q*64 + w*16 + srow
            int r = q * 64 + w * 16 + srow;
            int grow = m0 + r; if (grow >= M) grow = M - 1;
            gl_lds16(A + (size_t)grow * K + kk + scol, &sA[q * 2048 + w * 512 + lane * 8]);
        }
#pragma unroll
        for (int q = 0; q < 2; ++q) {  // B tile (Nn multiple of 128, no clamp)
            int r = q * 64 + w * 16 + srow;
            gl_lds16(Bt + (size_t)(n0 + r) * K + kk + scol, &sB[q * 2048 + w * 512 + lane * 8]);
        }
        __syncthreads();

        const int fr = lane & 15;
        const int fk = (lane >> 4) * 8;
        short8 af[4], bfr[4];
#pragma unroll
        for (int i = 0; i < 4; ++i)
            af[i] = *(const short8*)&sA[(wm + i * 16 + fr) * 32 + fk];
#pragma unroll
        for (int j = 0; j < 4; ++j)
            bfr[j] = *(const short8*)&sB[(wn + j * 16 + fr) * 32 + fk];
#pragma unroll
        for (int i = 0; i < 4; ++i)
#pragma unroll
            for (int j = 0; j < 4; ++j)
                acc[i][j] = __builtin_amdgcn_mfma_f32_16x16x32_bf16(
                    af[i], bfr[j], acc[i][j], 0, 0, 0);
        __syncthreads();
    }

    const int crow = (lane >> 4) * 4;
    const int ccol = lane & 15;
    // output base for the f32 path (wave tile is 64 cols -> entirely one side)
    float* fbase = Cf;
    int nb = n0 + wn;
    int stride = Nn;
    if (Cf2) {
        stride = split;
        if (nb >= split) { fbase = Cf2; nb -= split; }
    }
#pragma unroll
    for (int i = 0; i < 4; ++i) {
#pragma unroll
        for (int r = 0; r < 4; ++r) {
            int row = m0 + wm + i * 16 + crow + r;
            if (row >= M) continue;
            if (Cf) {
                float* cp = fbase + (size_t)row * stride + nb;
#pragma unroll
                for (int j = 0; j < 4; ++j) {
                    int c = j * 16 + ccol;
                    cp[c] = acc[i][j][r] + __bfloat162float(bias[n0 + wn + c]);
                }
            } else {
                bf16* cp = Cb + (size_t)row * Nn + n0 + wn;
#pragma unroll
                for (int j = 0; j < 4; ++j)
                    cp[j * 16 + ccol] = __float2bfloat16(acc[i][j][r]);
            }
        }
    }
}

// ---------------------------------------------------------------------------
// CSR gather: out[node] = sum_edges dinv[s]*dinv[node]*t[s] + dinv[node]^2*t[node]
// (+bias, relu if mode==1).
// One WAVE per node; each lane owns 8 consecutive bf16 feats (16B loads).
// 8-deep software pipeline: next group's col/dinv loads issue while current
// group's 8x1KB row loads are in flight (breaks the col->dinv->row chain).
// ---------------------------------------------------------------------------
__global__ __launch_bounds__(256) void gather_k(
    const bf16* __restrict__ t, const int* __restrict__ row_ptr,
    const int* __restrict__ col, const float* __restrict__ dinv,
    const bf16* __restrict__ bias, bf16* __restrict__ outp, int mode, int N) {
    const int node = blockIdx.x * 4 + (threadIdx.x >> 6);
    if (node >= N) return;
    const int lane = threadIdx.x & 63;
    const short8* tp = (const short8*)t;
    const int beg = row_ptr[node];
    const int end = row_ptr[node + 1];
    const float dv = dinv[node];
    float acc[8] = {0.f, 0.f, 0.f, 0.f, 0.f, 0.f, 0.f, 0.f};

    int e = beg;
    const int elim = beg + ((end - beg) & ~7);
    if (e < elim) {
        int c[8];
        float w[8];
#pragma unroll
        for (int k = 0; k < 8; ++k) c[k] = col[e + k];
#pragma unroll
        for (int k = 0; k < 8; ++k) w[k] = dinv[c[k]] * dv;
        for (;;) {
            short8 u[8];
#pragma unroll
            for (int k = 0; k < 8; ++k) u[k] = tp[(size_t)c[k] * 64 + lane];
            const int en = e + 8;
            const bool more = en < elim;
            int cn[8];
            float wn2[8];
            if (more) {
#pragma unroll
                for (int k = 0; k < 8; ++k) cn[k] = col[en + k];
#pragma unroll
                for (int k = 0; k < 8; ++k) wn2[k] = dinv[cn[k]] * dv;
            }
#pragma unroll
            for (int k = 0; k < 8; ++k) {
                const float wk = w[k];
#pragma unroll
                for (int j = 0; j < 8; ++j)
                    acc[j] += wk * bfu((unsigned short)u[k][j]);
            }
            e = en;
            if (!more) break;
#pragma unroll
            for (int k = 0; k < 8; ++k) { c[k] = cn[k]; w[k] = wn2[k]; }
        }
    }
    // remainder (<8 edges): unroll-4 then scalar
    for (; e + 4 <= end; e += 4) {
        int s0 = col[e + 0], s1 = col[e + 1], s2 = col[e + 2], s3 = col[e + 3];
        float w0 = dinv[s0] * dv, w1 = dinv[s1] * dv;
        float w2 = dinv[s2] * dv, w3 = dinv[s3] * dv;
        short8 u0 = tp[(size_t)s0 * 64 + lane];
        short8 u1 = tp[(size_t)s1 * 64 + lane];
        short8 u2 = tp[(size_t)s2 * 64 + lane];
        short8 u3 = tp[(size_t)s3 * 64 + lane];
#pragma unroll
        for (int k = 0; k < 8; ++k) {
            acc[k] += w0 * bfu((unsigned short)u0[k]);
            acc[k] += w1 * bfu((unsigned short)u1[k]);
            acc[k] += w2 * bfu((unsigned short)u2[k]);
            acc[k] += w3 * bfu((unsigned short)u3[k]);
        }
    }
    for (; e < end; ++e) {
        int s = col[e];
        float w = dinv[s] * dv;
        short8 u = tp[(size_t)s * 64 + lane];
#pragma unroll
        for (int k = 0; k < 8; ++k) acc[k] += w * bfu((unsigned short)u[k]);
    }
    {   // self loop
        short8 u = tp[(size_t)node * 64 + lane];
        float w = dv * dv;
#pragma unroll
        for (int k = 0; k < 8; ++k) acc[k] += w * bfu((unsigned short)u[k]);
    }
    if (mode == 1) {
        short8 bs = ((const short8*)bias)[lane];
#pragma unroll
        for (int k = 0; k < 8; ++k) {
            acc[k] += bfu((unsigned short)bs[k]);
            acc[k] = fmaxf(acc[k], 0.f);
        }
    }
    short8 o;
#pragma unroll
    for (int k = 0; k < 8; ++k) o[k] = (short)f2b(acc[k]);
    ((short8*)outp)[(size_t)node * 64 + lane] = o;
}

// ---------------------------------------------------------------------------
extern "C" void kernel_launch(void* const* d_in, const int* in_sizes, int n_in,
                              void* d_out, int out_size, void* d_ws, size_t ws_size,
                              hipStream_t stream) {
    const void* xin   = d_in[0];
    const void* ei    = d_in[1];
    const void* W1in  = d_in[2];
    const void* b1in  = d_in[3];
    const void* Wmuin = d_in[4];
    const void* bmuin = d_in[5];
    const void* Wlsin = d_in[6];
    const void* blsin = d_in[7];
    float* out = (float*)d_out;

    const int H    = in_sizes[3];        // 512
    const int DOUT = in_sizes[5];        // 256
    const int DIN  = in_sizes[2] / H;    // 512
    const int N    = in_sizes[0] / DIN;  // 50000
    const int E    = in_sizes[1] / 2;    // 800000
    const int G    = (N + 255) / 256;

    char* ws = (char*)d_ws;
    size_t off = 0;
    auto alloc = [&](size_t bytes) {
        void* p = ws + off;
        off = (off + bytes + 255) & ~(size_t)255;
        return p;
    };
    int*   flag    = (int*)alloc(256);
    int*   edges   = (int*)alloc((size_t)2 * E * 4);
    int*   degi    = (int*)alloc((size_t)N * 4);
    int*   row_ptr = (int*)alloc((size_t)(N + 1) * 4);
    int*   cnt     = (int*)alloc((size_t)N * 4);
    int*   partial = (int*)alloc((size_t)G * 4);
    int*   col     = (int*)alloc((size_t)E * 4);
    float* dinv    = (float*)alloc((size_t)N * 4);
    bf16*  t1      = (bf16*)alloc((size_t)N * H * 2);
    bf16*  g1      = (bf16*)alloc((size_t)N * H * 2);
    bf16*  xdrop   = (bf16*)alloc((size_t)N * DIN * 2);  // reused as h1
    bf16*  W1t     = (bf16*)alloc((size_t)DIN * H * 2);  // [H, DIN]
    bf16*  Wcat    = (bf16*)alloc((size_t)H * 2 * DOUT * 2); // [2*DOUT, H] rows: mu then ls
    bf16*  b1c     = (bf16*)alloc((size_t)H * 2);
    bf16*  bcat    = (bf16*)alloc((size_t)2 * DOUT * 2);
    if (off > ws_size) return;

    const int twoE = 2 * E;
    hipLaunchKernelGGL(detect_edges_k, dim3(1), dim3(256), 0, stream, (const unsigned*)ei, flag);
    hipLaunchKernelGGL(detect_f32_k, dim3(1), dim3(256), 0, stream, (const unsigned short*)xin, flag, 1);
    hipLaunchKernelGGL(detect_f32_k, dim3(1), dim3(256), 0, stream, (const unsigned short*)W1in, flag, 2);

    hipLaunchKernelGGL(convert_edges_k, dim3((twoE + 255) / 256), dim3(256), 0, stream,
                       ei, edges, twoE, flag);
    int n8 = (N * DIN) / 8;
    hipLaunchKernelGGL(canon_x_drop_k, dim3((n8 + 255) / 256), dim3(256), 0, stream,
                       xin, xdrop, n8, flag);
    hipLaunchKernelGGL(canon_transpose_k, dim3(DIN / 16, H / 16), dim3(16, 16), 0, stream,
                       W1in, (unsigned short*)W1t, DIN, H, flag, 2);
    hipLaunchKernelGGL(canon_transpose_k, dim3(H / 16, DOUT / 16), dim3(16, 16), 0, stream,
                       Wmuin, (unsigned short*)Wcat, H, DOUT, flag, 2);
    hipLaunchKernelGGL(canon_transpose_k, dim3(H / 16, DOUT / 16), dim3(16, 16), 0, stream,
                       Wlsin, (unsigned short*)(Wcat + (size_t)DOUT * H), H, DOUT, flag, 2);
    hipLaunchKernelGGL(canon_k, dim3(2), dim3(256), 0, stream, b1in, b1c, H, flag, 2);
    hipLaunchKernelGGL(canon_k, dim3(1), dim3(256), 0, stream, bmuin, bcat, DOUT, flag, 2);
    hipLaunchKernelGGL(canon_k, dim3(1), dim3(256), 0, stream, blsin, bcat + DOUT, DOUT, flag, 2);

    // CSR build
    hipLaunchKernelGGL(zero_int_k, dim3(G), dim3(256), 0, stream, degi, N);
    hipLaunchKernelGGL(zero_int_k, dim3(G), dim3(256), 0, stream, cnt, N);
    hipLaunchKernelGGL(deg_count_k, dim3((E + 255) / 256), dim3(256), 0, stream, edges, degi, E, N);
    hipLaunchKernelGGL(dinv_k, dim3(G), dim3(256), 0, stream, degi, dinv, N);
    hipLaunchKernelGGL(block_sums_k, dim3(G), dim3(256), 0, stream, degi, partial, N);
    hipLaunchKernelGGL(scan_partials_k, dim3(1), dim3(256), 0, stream, partial, G);
    hipLaunchKernelGGL(scan_block_k, dim3(G), dim3(256), 0, stream, degi, partial, row_ptr, N);
    hipLaunchKernelGGL(fill_k, dim3((E + 255) / 256), dim3(256), 0, stream, edges, row_ptr, cnt, col, E, N);

    // layer 1: t1 = xdrop @ W1 ; h1 = relu(gather(t1) + b1)
    hipLaunchKernelGGL(gemm_mfma_k, dim3((N + 127) / 128, H / 128), dim3(256), 0, stream,
                       xdrop, W1t, t1, (float*)nullptr, (float*)nullptr,
                       (const bf16*)nullptr, N, H, DIN, 0);
    bf16* h1 = xdrop;
    hipLaunchKernelGGL(gather_k, dim3((N + 3) / 4), dim3(256), 0, stream,
                       t1, row_ptr, col, dinv, b1c, h1, 1, N);

    // layer 2: g1 = gather(h1); [mu|logstd] = g1 @ [Wmu|Wls] + [bmu|bls] (fused)
    hipLaunchKernelGGL(gather_k, dim3((N + 3) / 4), dim3(256), 0, stream,
                       h1, row_ptr, col, dinv, (const bf16*)nullptr, g1, 0, N);
    hipLaunchKernelGGL(gemm_mfma_k, dim3((N + 127) / 128, (2 * DOUT) / 128), dim3(256), 0, stream,
                       g1, Wcat, (bf16*)nullptr, out, out + (size_t)N * DOUT,
                       bcat, N, 2 * DOUT, H, DOUT);
}